// Round 5
// baseline (155.897 us; speedup 1.0000x reference)
//
#include <hip/hip_runtime.h>

// Problem constants (fixed by the reference): x(16,3,512,512) fp32
#define HW_   (512 * 512)   // 262144 = 2^18
#define N_    16
#define C_    3
#define NHW_  (N_ * HW_)    // 4194304 = 2^22
#define BF_THRESH 0.5f

#define GRID1   1024        // 1024 blocks x 4 waves = 4096 waves (16/CU)
#define THREADS 256
#define NVEC    (NHW_ / 4)              // 1048576 float4 groups
#define STRIDE  (GRID1 * THREADS)       // 262144 threads -> exactly 4 groups/thread

__device__ __forceinline__ void wmse_accum(const float4& s,
                                           const float4& x0, const float4& a0,
                                           const float4& x1, const float4& a1,
                                           const float4& x2, const float4& a2,
                                           float& pos_sum, float& neg_sum, float& pos_cnt)
{
    const float p0 = s.x > BF_THRESH ? 1.0f : 0.0f;
    const float p1 = s.y > BF_THRESH ? 1.0f : 0.0f;
    const float p2 = s.z > BF_THRESH ? 1.0f : 0.0f;
    const float p3 = s.w > BF_THRESH ? 1.0f : 0.0f;
    pos_cnt += p0 + p1 + p2 + p3;

    float q0, q1, q2, q3, d0, d1, d2, d3, qsum, psum;

    d0 = a0.x - x0.x; d1 = a0.y - x0.y; d2 = a0.z - x0.z; d3 = a0.w - x0.w;
    q0 = d0 * d0; q1 = d1 * d1; q2 = d2 * d2; q3 = d3 * d3;
    qsum = q0 + q1 + q2 + q3;
    psum = q0 * p0 + q1 * p1 + q2 * p2 + q3 * p3;
    pos_sum += psum; neg_sum += qsum - psum;

    d0 = a1.x - x1.x; d1 = a1.y - x1.y; d2 = a1.z - x1.z; d3 = a1.w - x1.w;
    q0 = d0 * d0; q1 = d1 * d1; q2 = d2 * d2; q3 = d3 * d3;
    qsum = q0 + q1 + q2 + q3;
    psum = q0 * p0 + q1 * p1 + q2 * p2 + q3 * p3;
    pos_sum += psum; neg_sum += qsum - psum;

    d0 = a2.x - x2.x; d1 = a2.y - x2.y; d2 = a2.z - x2.z; d3 = a2.w - x2.w;
    q0 = d0 * d0; q1 = d1 * d1; q2 = d2 * d2; q3 = d3 * d3;
    qsum = q0 + q1 + q2 + q3;
    psum = q0 * p0 + q1 * p1 + q2 * p2 + q3 * p3;
    pos_sum += psum; neg_sum += qsum - psum;
}

// Load+accumulate two float4 groups (vA, vB); all 14 loads issued before compute.
__device__ __forceinline__ void wmse_batch2(
    const float* __restrict__ x, const float* __restrict__ ae,
    const float* __restrict__ seg, int vA, int vB,
    float& pos_sum, float& neg_sum, float& pos_cnt)
{
    const int posA = vA << 2;
    const int posB = vB << 2;
    const int nA = posA >> 18, hwA = posA & (HW_ - 1);
    const int nB = posB >> 18, hwB = posB & (HW_ - 1);
    const int baseA = nA * (C_ * HW_) + hwA;
    const int baseB = nB * (C_ * HW_) + hwB;

    const float4 sA  = *reinterpret_cast<const float4*>(seg + posA);
    const float4 sB  = *reinterpret_cast<const float4*>(seg + posB);
    const float4 xA0 = *reinterpret_cast<const float4*>(x  + baseA);
    const float4 aA0 = *reinterpret_cast<const float4*>(ae + baseA);
    const float4 xA1 = *reinterpret_cast<const float4*>(x  + baseA + HW_);
    const float4 aA1 = *reinterpret_cast<const float4*>(ae + baseA + HW_);
    const float4 xA2 = *reinterpret_cast<const float4*>(x  + baseA + 2 * HW_);
    const float4 aA2 = *reinterpret_cast<const float4*>(ae + baseA + 2 * HW_);
    const float4 xB0 = *reinterpret_cast<const float4*>(x  + baseB);
    const float4 aB0 = *reinterpret_cast<const float4*>(ae + baseB);
    const float4 xB1 = *reinterpret_cast<const float4*>(x  + baseB + HW_);
    const float4 aB1 = *reinterpret_cast<const float4*>(ae + baseB + HW_);
    const float4 xB2 = *reinterpret_cast<const float4*>(x  + baseB + 2 * HW_);
    const float4 aB2 = *reinterpret_cast<const float4*>(ae + baseB + 2 * HW_);

    wmse_accum(sA, xA0, aA0, xA1, aA1, xA2, aA2, pos_sum, neg_sum, pos_cnt);
    wmse_accum(sB, xB0, aB0, xB1, aB1, xB2, aB2, pos_sum, neg_sum, pos_cnt);
}

__global__ __launch_bounds__(THREADS) void wmse_reduce(
    const float* __restrict__ x,
    const float* __restrict__ ae,
    const float* __restrict__ seg,
    float* __restrict__ ws)   // ws[0..G): pos_sum, [G..2G): neg_sum, [2G..3G): cnt
{
    const int gtid = blockIdx.x * THREADS + threadIdx.x;

    float pos_sum = 0.0f, neg_sum = 0.0f, pos_cnt = 0.0f;

    // Exactly 4 groups/thread: v = gtid + k*STRIDE, k = 0..3, in two 2-group batches.
    wmse_batch2(x, ae, seg, gtid,              gtid +     STRIDE, pos_sum, neg_sum, pos_cnt);
    wmse_batch2(x, ae, seg, gtid + 2 * STRIDE, gtid + 3 * STRIDE, pos_sum, neg_sum, pos_cnt);

    // wave-64 shuffle tree
#pragma unroll
    for (int off = 32; off >= 1; off >>= 1) {
        pos_sum += __shfl_down(pos_sum, off, 64);
        neg_sum += __shfl_down(neg_sum, off, 64);
        pos_cnt += __shfl_down(pos_cnt, off, 64);
    }

    __shared__ float sp[4], sn[4], sc[4];
    const int wave = threadIdx.x >> 6;
    const int lane = threadIdx.x & 63;
    if (lane == 0) { sp[wave] = pos_sum; sn[wave] = neg_sum; sc[wave] = pos_cnt; }
    __syncthreads();
    if (threadIdx.x == 0) {
        ws[blockIdx.x]             = sp[0] + sp[1] + sp[2] + sp[3];
        ws[GRID1 + blockIdx.x]     = sn[0] + sn[1] + sn[2] + sn[3];
        ws[2 * GRID1 + blockIdx.x] = sc[0] + sc[1] + sc[2] + sc[3];
    }
}

__global__ __launch_bounds__(256) void wmse_stage2(
    const float* __restrict__ ws, float* __restrict__ out)
{
    float pos_sum = 0.0f, neg_sum = 0.0f, pos_cnt = 0.0f;
    for (int i = threadIdx.x; i < GRID1; i += 256) {
        pos_sum += ws[i];
        neg_sum += ws[GRID1 + i];
        pos_cnt += ws[2 * GRID1 + i];
    }

#pragma unroll
    for (int off = 32; off >= 1; off >>= 1) {
        pos_sum += __shfl_down(pos_sum, off, 64);
        neg_sum += __shfl_down(neg_sum, off, 64);
        pos_cnt += __shfl_down(pos_cnt, off, 64);
    }

    __shared__ float sp[4], sn[4], sc[4];
    const int wave = threadIdx.x >> 6;
    const int lane = threadIdx.x & 63;
    if (lane == 0) { sp[wave] = pos_sum; sn[wave] = neg_sum; sc[wave] = pos_cnt; }
    __syncthreads();
    if (threadIdx.x == 0) {
        const float tp = sp[0] + sp[1] + sp[2] + sp[3];
        const float tn = sn[0] + sn[1] + sn[2] + sn[3];
        const float tc = sc[0] + sc[1] + sc[2] + sc[3];

        const float total   = (float)NHW_;
        const float neg_num = total - tc;
        const float pos_ratio = tc / total;
        const float neg_ratio = 1.0f - pos_ratio;
        const float mse_pos = tp / (tc * (float)C_);
        const float mse_neg = tn / (neg_num * (float)C_);
        out[0] = pos_ratio * mse_neg + neg_ratio * mse_pos;
    }
}

extern "C" void kernel_launch(void* const* d_in, const int* in_sizes, int n_in,
                              void* d_out, int out_size, void* d_ws, size_t ws_size,
                              hipStream_t stream) {
    const float* x   = (const float*)d_in[0];
    const float* ae  = (const float*)d_in[1];
    const float* seg = (const float*)d_in[2];
    float* ws  = (float*)d_ws;
    float* out = (float*)d_out;

    // MEASUREMENT ROUND: launch the reduce twice. It overwrites (not
    // accumulates) ws partials, so the double launch is output-identical;
    // the bench-total delta vs R4 gives the reduce's exact duration, and
    // run #2 measures the L3-warm ceiling of this access pattern.
    wmse_reduce<<<GRID1, THREADS, 0, stream>>>(x, ae, seg, ws);
    wmse_reduce<<<GRID1, THREADS, 0, stream>>>(x, ae, seg, ws);
    wmse_stage2<<<1, 256, 0, stream>>>(ws, out);
}

// Round 6
// 135.725 us; speedup vs baseline: 1.1486x; 1.1486x over previous
//
#include <hip/hip_runtime.h>

// Problem constants (fixed by the reference): x(16,3,512,512) fp32
#define HW_   (512 * 512)   // 262144 floats/image/channel = 2^18
#define N_    16
#define C_    3
#define NHW_  (N_ * HW_)    // 4194304 = 2^22
#define BF_THRESH 0.5f

#define GRID1   1024        // 1024 blocks x 4 waves = 4096 waves (16/CU)
#define THREADS 256
#define NVEC    (NHW_ / 4)          // 1048576 float4 groups
#define GPB     (NVEC / GRID1)      // 1024 groups per block (contiguous)
// 64 blocks per image (65536 groups/image / 1024); each block is inside ONE n.

__device__ __forceinline__ void wmse_accum(const float4& s,
                                           const float4& x0, const float4& a0,
                                           const float4& x1, const float4& a1,
                                           const float4& x2, const float4& a2,
                                           float& pos_sum, float& neg_sum, float& pos_cnt)
{
    const float p0 = s.x > BF_THRESH ? 1.0f : 0.0f;
    const float p1 = s.y > BF_THRESH ? 1.0f : 0.0f;
    const float p2 = s.z > BF_THRESH ? 1.0f : 0.0f;
    const float p3 = s.w > BF_THRESH ? 1.0f : 0.0f;
    pos_cnt += p0 + p1 + p2 + p3;

    float q0, q1, q2, q3, d0, d1, d2, d3, qsum, psum;

    d0 = a0.x - x0.x; d1 = a0.y - x0.y; d2 = a0.z - x0.z; d3 = a0.w - x0.w;
    q0 = d0 * d0; q1 = d1 * d1; q2 = d2 * d2; q3 = d3 * d3;
    qsum = q0 + q1 + q2 + q3;
    psum = q0 * p0 + q1 * p1 + q2 * p2 + q3 * p3;
    pos_sum += psum; neg_sum += qsum - psum;

    d0 = a1.x - x1.x; d1 = a1.y - x1.y; d2 = a1.z - x1.z; d3 = a1.w - x1.w;
    q0 = d0 * d0; q1 = d1 * d1; q2 = d2 * d2; q3 = d3 * d3;
    qsum = q0 + q1 + q2 + q3;
    psum = q0 * p0 + q1 * p1 + q2 * p2 + q3 * p3;
    pos_sum += psum; neg_sum += qsum - psum;

    d0 = a2.x - x2.x; d1 = a2.y - x2.y; d2 = a2.z - x2.z; d3 = a2.w - x2.w;
    q0 = d0 * d0; q1 = d1 * d1; q2 = d2 * d2; q3 = d3 * d3;
    qsum = q0 + q1 + q2 + q3;
    psum = q0 * p0 + q1 * p1 + q2 * p2 + q3 * p3;
    pos_sum += psum; neg_sum += qsum - psum;
}

// Two k-chunks: offsets offA/offB (floats) from the block-uniform bases.
__device__ __forceinline__ void wmse_batch2(
    const float* __restrict__ segb,
    const float* __restrict__ xb,
    const float* __restrict__ aeb,
    int offA, int offB,
    float& pos_sum, float& neg_sum, float& pos_cnt)
{
    const float4 sA  = *reinterpret_cast<const float4*>(segb + offA);
    const float4 sB  = *reinterpret_cast<const float4*>(segb + offB);
    const float4 xA0 = *reinterpret_cast<const float4*>(xb  + offA);
    const float4 aA0 = *reinterpret_cast<const float4*>(aeb + offA);
    const float4 xA1 = *reinterpret_cast<const float4*>(xb  + offA + HW_);
    const float4 aA1 = *reinterpret_cast<const float4*>(aeb + offA + HW_);
    const float4 xA2 = *reinterpret_cast<const float4*>(xb  + offA + 2 * HW_);
    const float4 aA2 = *reinterpret_cast<const float4*>(aeb + offA + 2 * HW_);
    const float4 xB0 = *reinterpret_cast<const float4*>(xb  + offB);
    const float4 aB0 = *reinterpret_cast<const float4*>(aeb + offB);
    const float4 xB1 = *reinterpret_cast<const float4*>(xb  + offB + HW_);
    const float4 aB1 = *reinterpret_cast<const float4*>(aeb + offB + HW_);
    const float4 xB2 = *reinterpret_cast<const float4*>(xb  + offB + 2 * HW_);
    const float4 aB2 = *reinterpret_cast<const float4*>(aeb + offB + 2 * HW_);

    wmse_accum(sA, xA0, aA0, xA1, aA1, xA2, aA2, pos_sum, neg_sum, pos_cnt);
    wmse_accum(sB, xB0, aB0, xB1, aB1, xB2, aB2, pos_sum, neg_sum, pos_cnt);
}

__global__ __launch_bounds__(THREADS) void wmse_reduce(
    const float* __restrict__ x,
    const float* __restrict__ ae,
    const float* __restrict__ seg,
    float* __restrict__ ws)   // ws[0..G): pos_sum, [G..2G): neg_sum, [2G..3G): cnt
{
    // Block-uniform (SGPR) bases: block b owns contiguous groups [b*GPB,(b+1)*GPB),
    // which lie inside image n = b/64.
    const int n     = blockIdx.x >> 6;                 // 64 blocks per image
    const int hw0   = (blockIdx.x & 63) << 12;         // (b%64)*1024 groups *4 floats
    const float* segb = seg + (n << 18) + hw0;         // n*HW_ + hw0
    const float* xb   = x   + n * (C_ * HW_) + hw0;
    const float* aeb  = ae  + n * (C_ * HW_) + hw0;

    // Thread's float offset inside the block's 16 KB-per-stream run:
    // k-chunk stride = 256 groups * 4 floats = 1024.
    const int t4 = threadIdx.x << 2;

    float pos_sum = 0.0f, neg_sum = 0.0f, pos_cnt = 0.0f;
    wmse_batch2(segb, xb, aeb, t4,        t4 + 1024, pos_sum, neg_sum, pos_cnt);
    wmse_batch2(segb, xb, aeb, t4 + 2048, t4 + 3072, pos_sum, neg_sum, pos_cnt);

    // wave-64 shuffle tree
#pragma unroll
    for (int off = 32; off >= 1; off >>= 1) {
        pos_sum += __shfl_down(pos_sum, off, 64);
        neg_sum += __shfl_down(neg_sum, off, 64);
        pos_cnt += __shfl_down(pos_cnt, off, 64);
    }

    __shared__ float sp[4], sn[4], sc[4];
    const int wave = threadIdx.x >> 6;
    const int lane = threadIdx.x & 63;
    if (lane == 0) { sp[wave] = pos_sum; sn[wave] = neg_sum; sc[wave] = pos_cnt; }
    __syncthreads();
    if (threadIdx.x == 0) {
        ws[blockIdx.x]             = sp[0] + sp[1] + sp[2] + sp[3];
        ws[GRID1 + blockIdx.x]     = sn[0] + sn[1] + sn[2] + sn[3];
        ws[2 * GRID1 + blockIdx.x] = sc[0] + sc[1] + sc[2] + sc[3];
    }
}

__global__ __launch_bounds__(256) void wmse_stage2(
    const float* __restrict__ ws, float* __restrict__ out)
{
    float pos_sum = 0.0f, neg_sum = 0.0f, pos_cnt = 0.0f;
    for (int i = threadIdx.x; i < GRID1; i += 256) {
        pos_sum += ws[i];
        neg_sum += ws[GRID1 + i];
        pos_cnt += ws[2 * GRID1 + i];
    }

#pragma unroll
    for (int off = 32; off >= 1; off >>= 1) {
        pos_sum += __shfl_down(pos_sum, off, 64);
        neg_sum += __shfl_down(neg_sum, off, 64);
        pos_cnt += __shfl_down(pos_cnt, off, 64);
    }

    __shared__ float sp[4], sn[4], sc[4];
    const int wave = threadIdx.x >> 6;
    const int lane = threadIdx.x & 63;
    if (lane == 0) { sp[wave] = pos_sum; sn[wave] = neg_sum; sc[wave] = pos_cnt; }
    __syncthreads();
    if (threadIdx.x == 0) {
        const float tp = sp[0] + sp[1] + sp[2] + sp[3];
        const float tn = sn[0] + sn[1] + sn[2] + sn[3];
        const float tc = sc[0] + sc[1] + sc[2] + sc[3];

        const float total   = (float)NHW_;
        const float neg_num = total - tc;
        const float pos_ratio = tc / total;
        const float neg_ratio = 1.0f - pos_ratio;
        const float mse_pos = tp / (tc * (float)C_);
        const float mse_neg = tn / (neg_num * (float)C_);
        out[0] = pos_ratio * mse_neg + neg_ratio * mse_pos;
    }
}

extern "C" void kernel_launch(void* const* d_in, const int* in_sizes, int n_in,
                              void* d_out, int out_size, void* d_ws, size_t ws_size,
                              hipStream_t stream) {
    const float* x   = (const float*)d_in[0];
    const float* ae  = (const float*)d_in[1];
    const float* seg = (const float*)d_in[2];
    float* ws  = (float*)d_ws;
    float* out = (float*)d_out;

    wmse_reduce<<<GRID1, THREADS, 0, stream>>>(x, ae, seg, ws);
    wmse_stage2<<<1, 256, 0, stream>>>(ws, out);
}

// Round 7
// 131.521 us; speedup vs baseline: 1.1853x; 1.0320x over previous
//
#include <hip/hip_runtime.h>

// Problem constants (fixed by the reference): x(16,3,512,512) fp32
#define HW_   (512 * 512)   // 262144 floats/image/channel = 2^18
#define N_    16
#define C_    3
#define NHW_  (N_ * HW_)    // 4194304 = 2^22
#define BF_THRESH 0.5f

#define GRID1   1024        // 1024 blocks x 4 waves = 4096 waves (16/CU)
#define THREADS 256
#define NVEC    (NHW_ / 4)          // 1048576 float4 groups
#define GPB     (NVEC / GRID1)      // 1024 groups per block (contiguous)

// Native vector type so __builtin_nontemporal_load works (emits nt-flagged
// global_load_dwordx4: no cache allocation on miss; hits still hit).
typedef float vfloat4 __attribute__((ext_vector_type(4)));

__device__ __forceinline__ vfloat4 nt_load(const float* p) {
    return __builtin_nontemporal_load(reinterpret_cast<const vfloat4*>(p));
}

__device__ __forceinline__ void wmse_accum(const vfloat4& s,
                                           const vfloat4& x0, const vfloat4& a0,
                                           const vfloat4& x1, const vfloat4& a1,
                                           const vfloat4& x2, const vfloat4& a2,
                                           float& pos_sum, float& neg_sum, float& pos_cnt)
{
    const float p0 = s.x > BF_THRESH ? 1.0f : 0.0f;
    const float p1 = s.y > BF_THRESH ? 1.0f : 0.0f;
    const float p2 = s.z > BF_THRESH ? 1.0f : 0.0f;
    const float p3 = s.w > BF_THRESH ? 1.0f : 0.0f;
    pos_cnt += p0 + p1 + p2 + p3;

    float q0, q1, q2, q3, d0, d1, d2, d3, qsum, psum;

    d0 = a0.x - x0.x; d1 = a0.y - x0.y; d2 = a0.z - x0.z; d3 = a0.w - x0.w;
    q0 = d0 * d0; q1 = d1 * d1; q2 = d2 * d2; q3 = d3 * d3;
    qsum = q0 + q1 + q2 + q3;
    psum = q0 * p0 + q1 * p1 + q2 * p2 + q3 * p3;
    pos_sum += psum; neg_sum += qsum - psum;

    d0 = a1.x - x1.x; d1 = a1.y - x1.y; d2 = a1.z - x1.z; d3 = a1.w - x1.w;
    q0 = d0 * d0; q1 = d1 * d1; q2 = d2 * d2; q3 = d3 * d3;
    qsum = q0 + q1 + q2 + q3;
    psum = q0 * p0 + q1 * p1 + q2 * p2 + q3 * p3;
    pos_sum += psum; neg_sum += qsum - psum;

    d0 = a2.x - x2.x; d1 = a2.y - x2.y; d2 = a2.z - x2.z; d3 = a2.w - x2.w;
    q0 = d0 * d0; q1 = d1 * d1; q2 = d2 * d2; q3 = d3 * d3;
    qsum = q0 + q1 + q2 + q3;
    psum = q0 * p0 + q1 * p1 + q2 * p2 + q3 * p3;
    pos_sum += psum; neg_sum += qsum - psum;
}

// Two k-chunks: offsets offA/offB (floats) from the block-uniform bases.
__device__ __forceinline__ void wmse_batch2(
    const float* __restrict__ segb,
    const float* __restrict__ xb,
    const float* __restrict__ aeb,
    int offA, int offB,
    float& pos_sum, float& neg_sum, float& pos_cnt)
{
    const vfloat4 sA  = nt_load(segb + offA);
    const vfloat4 sB  = nt_load(segb + offB);
    const vfloat4 xA0 = nt_load(xb  + offA);
    const vfloat4 aA0 = nt_load(aeb + offA);
    const vfloat4 xA1 = nt_load(xb  + offA + HW_);
    const vfloat4 aA1 = nt_load(aeb + offA + HW_);
    const vfloat4 xA2 = nt_load(xb  + offA + 2 * HW_);
    const vfloat4 aA2 = nt_load(aeb + offA + 2 * HW_);
    const vfloat4 xB0 = nt_load(xb  + offB);
    const vfloat4 aB0 = nt_load(aeb + offB);
    const vfloat4 xB1 = nt_load(xb  + offB + HW_);
    const vfloat4 aB1 = nt_load(aeb + offB + HW_);
    const vfloat4 xB2 = nt_load(xb  + offB + 2 * HW_);
    const vfloat4 aB2 = nt_load(aeb + offB + 2 * HW_);

    wmse_accum(sA, xA0, aA0, xA1, aA1, xA2, aA2, pos_sum, neg_sum, pos_cnt);
    wmse_accum(sB, xB0, aB0, xB1, aB1, xB2, aB2, pos_sum, neg_sum, pos_cnt);
}

__global__ __launch_bounds__(THREADS) void wmse_reduce(
    const float* __restrict__ x,
    const float* __restrict__ ae,
    const float* __restrict__ seg,
    float* __restrict__ ws)   // ws[0..G): pos_sum, [G..2G): neg_sum, [2G..3G): cnt
{
    // Block-uniform (SGPR) bases: block b owns contiguous groups [b*GPB,(b+1)*GPB),
    // inside image n = b/64.
    const int n     = blockIdx.x >> 6;                 // 64 blocks per image
    const int hw0   = (blockIdx.x & 63) << 12;         // (b%64)*1024 groups *4 floats
    const float* segb = seg + (n << 18) + hw0;
    const float* xb   = x   + n * (C_ * HW_) + hw0;
    const float* aeb  = ae  + n * (C_ * HW_) + hw0;

    const int t4 = threadIdx.x << 2;   // k-chunk stride = 1024 floats

    float pos_sum = 0.0f, neg_sum = 0.0f, pos_cnt = 0.0f;
    wmse_batch2(segb, xb, aeb, t4,        t4 + 1024, pos_sum, neg_sum, pos_cnt);
    wmse_batch2(segb, xb, aeb, t4 + 2048, t4 + 3072, pos_sum, neg_sum, pos_cnt);

    // wave-64 shuffle tree
#pragma unroll
    for (int off = 32; off >= 1; off >>= 1) {
        pos_sum += __shfl_down(pos_sum, off, 64);
        neg_sum += __shfl_down(neg_sum, off, 64);
        pos_cnt += __shfl_down(pos_cnt, off, 64);
    }

    __shared__ float sp[4], sn[4], sc[4];
    const int wave = threadIdx.x >> 6;
    const int lane = threadIdx.x & 63;
    if (lane == 0) { sp[wave] = pos_sum; sn[wave] = neg_sum; sc[wave] = pos_cnt; }
    __syncthreads();
    if (threadIdx.x == 0) {
        ws[blockIdx.x]             = sp[0] + sp[1] + sp[2] + sp[3];
        ws[GRID1 + blockIdx.x]     = sn[0] + sn[1] + sn[2] + sn[3];
        ws[2 * GRID1 + blockIdx.x] = sc[0] + sc[1] + sc[2] + sc[3];
    }
}

__global__ __launch_bounds__(256) void wmse_stage2(
    const float* __restrict__ ws, float* __restrict__ out)
{
    float pos_sum = 0.0f, neg_sum = 0.0f, pos_cnt = 0.0f;
    for (int i = threadIdx.x; i < GRID1; i += 256) {
        pos_sum += ws[i];
        neg_sum += ws[GRID1 + i];
        pos_cnt += ws[2 * GRID1 + i];
    }

#pragma unroll
    for (int off = 32; off >= 1; off >>= 1) {
        pos_sum += __shfl_down(pos_sum, off, 64);
        neg_sum += __shfl_down(neg_sum, off, 64);
        pos_cnt += __shfl_down(pos_cnt, off, 64);
    }

    __shared__ float sp[4], sn[4], sc[4];
    const int wave = threadIdx.x >> 6;
    const int lane = threadIdx.x & 63;
    if (lane == 0) { sp[wave] = pos_sum; sn[wave] = neg_sum; sc[wave] = pos_cnt; }
    __syncthreads();
    if (threadIdx.x == 0) {
        const float tp = sp[0] + sp[1] + sp[2] + sp[3];
        const float tn = sn[0] + sn[1] + sn[2] + sn[3];
        const float tc = sc[0] + sc[1] + sc[2] + sc[3];

        const float total   = (float)NHW_;
        const float neg_num = total - tc;
        const float pos_ratio = tc / total;
        const float neg_ratio = 1.0f - pos_ratio;
        const float mse_pos = tp / (tc * (float)C_);
        const float mse_neg = tn / (neg_num * (float)C_);
        out[0] = pos_ratio * mse_neg + neg_ratio * mse_pos;
    }
}

extern "C" void kernel_launch(void* const* d_in, const int* in_sizes, int n_in,
                              void* d_out, int out_size, void* d_ws, size_t ws_size,
                              hipStream_t stream) {
    const float* x   = (const float*)d_in[0];
    const float* ae  = (const float*)d_in[1];
    const float* seg = (const float*)d_in[2];
    float* ws  = (float*)d_ws;
    float* out = (float*)d_out;

    wmse_reduce<<<GRID1, THREADS, 0, stream>>>(x, ae, seg, ws);
    wmse_stage2<<<1, 256, 0, stream>>>(ws, out);
}